// Round 13
// baseline (237.906 us; speedup 1.0000x reference)
//
#include <hip/hip_runtime.h>

typedef __attribute__((ext_vector_type(8))) short short8;
typedef __attribute__((ext_vector_type(4))) float f32x4;
typedef __attribute__((ext_vector_type(16))) float f32x16;
typedef __attribute__((ext_vector_type(4))) unsigned int u32x4;

#define NTOK 4096
#define DIM  256
#define P_STRIDE 72        // P row stride elems (144 B); chunk kc at pos = kc ^ (2*((r>>3)&1))
#define TILE_ELEMS 32768   // ushort elems per 64KB tile image (Ks 16384 | Kt 16384)

__device__ __forceinline__ unsigned pack2bf(float a, float b) {
  unsigned ua = __builtin_bit_cast(unsigned, a) + 0x8000u;
  unsigned ub = __builtin_bit_cast(unsigned, b) + 0x8000u;
  return __builtin_amdgcn_perm(ub, ua, 0x07060302u); // low=bf16(a), high=bf16(b)
}

// ---- prologue v2: single X read, LDS-staged transpose (verified R3) ------
__global__ __launch_bounds__(256, 4)
void prep_kernel(const float* __restrict__ X, unsigned short* __restrict__ Img) {
  __shared__ __align__(16) unsigned short rowbf[8 * 256];  // 4 KB bf16 stage
  const int b    = blockIdx.x & 3;
  const int sub  = blockIdx.x >> 2;   // 0..511
  const int t    = sub >> 3;
  const int part = sub & 7;
  const int tid  = threadIdx.x;
  const float* src = X + ((size_t)b * NTOK + t * 64 + part * 8) * DIM;
  unsigned short* dst = Img + ((size_t)(b * 64 + t)) * TILE_ELEMS;
  {
    const int r = tid >> 5;   // row within the 8-row slab
    const int c = tid & 31;   // 16B chunk within the row
    const float* s = src + r * DIM + c * 8;
    f32x4 f0 = *(const f32x4*)s;
    f32x4 f1 = *(const f32x4*)(s + 4);
    union { unsigned u[4]; u32x4 v; } p;
    p.u[0] = pack2bf(f0[0], f0[1]);
    p.u[1] = pack2bf(f0[2], f0[3]);
    p.u[2] = pack2bf(f1[0], f1[1]);
    p.u[3] = pack2bf(f1[2], f1[3]);
    const int gr = part * 8 + r;
    *(u32x4*)(dst + gr * 256 + ((c ^ (gr & 7)) << 3)) = p.v;
    *(u32x4*)(&rowbf[r * 256 + c * 8]) = p.v;
  }
  __syncthreads();
  {
    const int d = tid;        // one column per thread
    union { unsigned short s[8]; u32x4 v; } p;
    #pragma unroll
    for (int i = 0; i < 8; ++i) p.s[i] = rowbf[i * 256 + d];
    *(u32x4*)(dst + 16384 + part * 2048 + d * 8) = p.v;
  }
}

// ---- flash-attention v13: R10 (verified 75.9us) + 32x32 PV MFMA ----------
// R12: XCD grouping slightly negative -> reverted; K-latency theory dead.
// R10 sits at ~23 B/cyc/CU L2 traffic (near fabric plateau) and MFMA+VALU =
// 71%. Remaining cut: PV cluster 32x 16x16x32 (620cyc/SIMD) -> 16x 32x32x16
// (516cyc, -17% MFMA pipe). All fragment maps HW-verified in R6:
//   A: row=lane&31, k=h*8+e  -> P chunk kc = ks2*2+h (2-way bank = free)
//   B: col=lane&31           -> Kt addr kb*2048 + d*8, kb = ks2*2+h
//   D: col=lane&31, row=(reg&3)+8*(reg>>2)+4*h
// QK path + P image byte-identical; register footprint conserved (o: 64
// regs as 4x f32x16; V sets 64 regs unchanged) -- no R11 spill exposure.
#define PV_TAIL32(PRD, SB)                                                     \
  {                                                                            \
    const unsigned short* prd = (PRD);                                         \
    _Pragma("unroll")                                                          \
    for (int ks2 = 0; ks2 < 4; ++ks2) {                                        \
      const int pos = (ks2 * 2 + h) ^ (((l31 >> 3) & 1) << 1);                 \
      short8 ap0 = *(const short8*)(&prd[l31 * P_STRIDE + (pos << 3)]);        \
      short8 ap1 = *(const short8*)(&prd[(32 + l31) * P_STRIDE + (pos << 3)]); \
      oA = __builtin_amdgcn_mfma_f32_32x32x16_bf16(ap0,                        \
             __builtin_bit_cast(short8, u[(SB) + ks2 * 2 + 0]), oA, 0, 0, 0);  \
      oB = __builtin_amdgcn_mfma_f32_32x32x16_bf16(ap0,                        \
             __builtin_bit_cast(short8, u[(SB) + ks2 * 2 + 1]), oB, 0, 0, 0);  \
      oC = __builtin_amdgcn_mfma_f32_32x32x16_bf16(ap1,                        \
             __builtin_bit_cast(short8, u[(SB) + ks2 * 2 + 0]), oC, 0, 0, 0);  \
      oD = __builtin_amdgcn_mfma_f32_32x32x16_bf16(ap1,                        \
             __builtin_bit_cast(short8, u[(SB) + ks2 * 2 + 1]), oD, 0, 0, 0);  \
    }                                                                          \
  }

#define FA_STEP(T, SETB)                                                       \
  {                                                                            \
    const int t_ = (T);                                                        \
    __syncthreads();  /* publishes P(t-2) in pb[t&1]; orders pb reuse */       \
    if (!isQK) {                                                               \
      if (t_ > 1) {                                                            \
        __builtin_amdgcn_s_setprio(1);                                         \
        PV_TAIL32(pb[t_ & 1], SETB);   /* P(t-2) x V(t-2) */                   \
        __builtin_amdgcn_s_setprio(0);                                         \
      }                                                                        \
      { /* reload set with V(t); consumed at t+2 -> 2 iters to land */         \
        const unsigned short* vt = vtg + (size_t)t_ * TILE_ELEMS;              \
        _Pragma("unroll")                                                      \
        for (int ks2 = 0; ks2 < 4; ++ks2)                                      \
          _Pragma("unroll")                                                    \
          for (int d2 = 0; d2 < 2; ++d2)                                       \
            u[(SETB) + ks2 * 2 + d2] = __builtin_bit_cast(f32x4,               \
                *(const short8*)(vt + (ks2 * 2 + h) * 2048 + d2 * 256));       \
      }                                                                        \
    } else {                                                                   \
      /* 1) issue K(t) loads (L2/L3-hot) */                                    \
      const unsigned short* kR =                                               \
          imgb + (size_t)t_ * TILE_ELEMS + (role * 16 + ln) * 256;             \
      short8 bk[8];                                                            \
      _Pragma("unroll")                                                        \
      for (int ds = 0; ds < 8; ++ds)                                           \
        bk[ds] = *(const short8*)(kR + (((ds * 4 + quad) ^ swz) << 3));        \
      /* 2) deferred softmax of tile t-1 (VALU; overlaps K latency+MFMA) */    \
      if (t_ > 0) expstore((t_ & 1) ^ 1);                                      \
      /* 3) QK MFMA into sfo (first ds starts from zero) */                    \
      __builtin_amdgcn_s_setprio(1);                                           \
      _Pragma("unroll")                                                        \
      for (int s = 0; s < 4; ++s)                                              \
        sfo[s] = __builtin_amdgcn_mfma_f32_16x16x32_bf16(                      \
            __builtin_bit_cast(short8, u[s * 8]), bk[0], (f32x4)(0.0f),        \
            0, 0, 0);                                                          \
      _Pragma("unroll")                                                        \
      for (int ds = 1; ds < 8; ++ds)                                           \
        _Pragma("unroll")                                                      \
        for (int s = 0; s < 4; ++s)                                            \
          sfo[s] = __builtin_amdgcn_mfma_f32_16x16x32_bf16(                    \
              __builtin_bit_cast(short8, u[s * 8 + ds]), bk[ds], sfo[s],       \
              0, 0, 0);                                                        \
      __builtin_amdgcn_s_setprio(0);                                           \
    }                                                                          \
  }

__global__ __launch_bounds__(512, 1)
void fa_kernel(const unsigned short* __restrict__ Img, float* __restrict__ Out) {
  __shared__ __align__(16) unsigned short pb[2][64 * P_STRIDE]; // 18 KB P dbuf
  __shared__ float lbuf[64][4];                                 // 1 KB

  const int tid  = threadIdx.x;
  const int b    = blockIdx.x & 3;   // R10 mapping (R12's grouping reverted)
  const int qblk = blockIdx.x >> 2;
  const int wave = tid >> 6;
  const int lane = tid & 63;
  const int ln   = lane & 15;
  const int quad = lane >> 4;
  const int swz  = ln & 7;
  const int l31  = lane & 31;        // PV 32x32: row/col index
  const int h    = lane >> 5;        // PV 32x32: k-half
  const bool isQK = wave < 4;
  const int  role = wave & 3;  // QK: key-16 group; PV: d-quarter

  const unsigned short* imgb = Img + (size_t)b * 64 * TILE_ELEMS;

  const float c2 = 0.0901684400f;  // log2(e)/sqrt(256)

  // P write constants (QK waves): kc = role*2 + (ln>>3); pos = kc ^ (2*(quad>>1))
  const int pwPos = ((role * 2 + (ln >> 3)) ^ ((quad >> 1) << 1)) << 3;
  const int pwCol = ln & 7;

  // PV: V-frag base in Kt image (32x32 B-frag: d-col = l31)
  const unsigned short* vtg = imgb + 16384 + (size_t)(role * 64 + l31) * 8;

  float lrow[4][4] = {{0,0,0,0},{0,0,0,0},{0,0,0,0},{0,0,0,0}};
  f32x4 sfo[4];   // QK: scores of the PREVIOUS tile (deferred softmax)
  f32x16 oA, oB, oC, oD;  // PV accumulators: (s2,d2) = (0,0),(0,1),(1,0),(1,1)

  // Register overlay: QK waves -> aQ[s][ds] = u[s*8+ds] (u[16..31] untouched);
  //                   PV waves -> V sets at u[16..23] / u[24..31] (u[0..15] untouched)
  f32x4 u[32];
  if (isQK) {
    #pragma unroll
    for (int s = 0; s < 4; ++s) {
      const unsigned short* qrow =
          imgb + (size_t)qblk * TILE_ELEMS + (s * 16 + ln) * 256;
      #pragma unroll
      for (int ds = 0; ds < 8; ++ds)
        u[s * 8 + ds] = __builtin_bit_cast(f32x4,
            *(const short8*)(qrow + (((ds * 4 + quad) ^ swz) << 3)));
    }
  } else {
    oA = (f32x16)(0.0f); oB = (f32x16)(0.0f);
    oC = (f32x16)(0.0f); oD = (f32x16)(0.0f);
  }

  // deferred-softmax of sfo -> pb[pwbuf] (QK waves only)
  auto expstore = [&](int pwbuf) __attribute__((always_inline)) {
    unsigned short* pw = pb[pwbuf];
    #pragma unroll
    for (int s = 0; s < 4; ++s) {
      unsigned pd[4];
      #pragma unroll
      for (int j = 0; j < 4; ++j) {
        float p0 = __builtin_amdgcn_exp2f(sfo[s][j] * c2);
        lrow[s][j] += p0;
        unsigned q0 = __builtin_bit_cast(unsigned, p0);
        unsigned n0 = (unsigned)__builtin_amdgcn_mov_dpp((int)q0, 0xB1,
                                                         0xF, 0xF, true);
        pd[j] = pack2bf(p0, __builtin_bit_cast(float, n0));
      }
      if ((ln & 1) == 0) {
        #pragma unroll
        for (int j = 0; j < 4; ++j)
          *(unsigned*)(&pw[(s * 16 + quad * 4 + j) * P_STRIDE +
                           pwPos + pwCol]) = pd[j];
      }
    }
  };

  #pragma unroll 1
  for (int tt = 0; tt < 64; tt += 2) {
    FA_STEP(tt, 16);       // even t: V set base 16
    FA_STEP(tt + 1, 24);   // odd  t: V set base 24
  }
  // state: P(62) in pb[0] (stored at t=63); sfo = sf(63);
  //        V(62) in set 16, V(63) in set 24.

  __syncthreads();  // publishes P(62)
  if (isQK) {
    expstore(1);    // P(63) -> pb[1]
  } else {
    PV_TAIL32(pb[0], 16);  // P(62) x V(62)
  }
  __syncthreads();  // publishes P(63)

  if (isQK) {
    // merge l over the 16 key-lanes of this role
    #pragma unroll
    for (int off = 1; off < 16; off <<= 1)
      #pragma unroll
      for (int s = 0; s < 4; ++s)
        #pragma unroll
        for (int j = 0; j < 4; ++j)
          lrow[s][j] += __shfl_xor(lrow[s][j], off, 64);
    if (ln == 0) {
      #pragma unroll
      for (int s = 0; s < 4; ++s)
        #pragma unroll
        for (int j = 0; j < 4; ++j)
          lbuf[s * 16 + quad * 4 + j][role] = lrow[s][j];
    }
  } else {
    PV_TAIL32(pb[1], 24);  // P(63) x V(63)
  }
  __syncthreads();  // lbuf ready

  if (!isQK) {
    // D layout: col = l31, row = (r&3) + 8*(r>>2) + 4*h (+32 for s2=1)
    float* outB = Out + (size_t)(b * NTOK + qblk * 64) * DIM + role * 64;
    #pragma unroll
    for (int r = 0; r < 16; ++r) {
      const int row0 = (r & 3) + 8 * (r >> 2) + 4 * h;
      {
        f32x4 lv = *(const f32x4*)lbuf[row0];
        const float rl = 1.0f / (lv[0] + lv[1] + lv[2] + lv[3]);
        outB[(size_t)row0 * DIM + l31]      = oA[r] * rl;
        outB[(size_t)row0 * DIM + 32 + l31] = oB[r] * rl;
      }
      {
        const int row1 = row0 + 32;
        f32x4 lv = *(const f32x4*)lbuf[row1];
        const float rl = 1.0f / (lv[0] + lv[1] + lv[2] + lv[3]);
        outB[(size_t)row1 * DIM + l31]      = oC[r] * rl;
        outB[(size_t)row1 * DIM + 32 + l31] = oD[r] * rl;
      }
    }
  }
}

extern "C" void kernel_launch(void* const* d_in, const int* in_sizes, int n_in,
                              void* d_out, int out_size, void* d_ws, size_t ws_size,
                              hipStream_t stream) {
  const float* X = (const float*)d_in[0];       // x: fp32 [4,4096,256]
  float* Out = (float*)d_out;                   // fp32 [4,4096,256]
  unsigned short* Img = (unsigned short*)d_ws;  // 16 MB bf16 tile images
  (void)in_sizes; (void)n_in; (void)out_size; (void)ws_size;
  hipLaunchKernelGGL(prep_kernel, dim3(2048), dim3(256), 0, stream, X, Img);
  hipLaunchKernelGGL(fa_kernel, dim3(256), dim3(512), 0, stream, Img, Out);
}

// Round 15
// 144.072 us; speedup vs baseline: 1.6513x; 1.6513x over previous
//
#include <hip/hip_runtime.h>

typedef __attribute__((ext_vector_type(8))) short short8;
typedef __attribute__((ext_vector_type(4))) float f32x4;
typedef __attribute__((ext_vector_type(4))) unsigned int u32x4;

#define NTOK 4096
#define DIM  256
#define P_STRIDE 72        // P row stride elems (144 B); chunk kc at pos = kc ^ (2*((r>>3)&1))
#define TILE_ELEMS 32768   // ushort elems per 64KB tile image (Ks 16384 | Kt 16384)

__device__ __forceinline__ unsigned pack2bf(float a, float b) {
  unsigned ua = __builtin_bit_cast(unsigned, a) + 0x8000u;
  unsigned ub = __builtin_bit_cast(unsigned, b) + 0x8000u;
  return __builtin_amdgcn_perm(ub, ua, 0x07060302u); // low=bf16(a), high=bf16(b)
}

// ---- prologue v2: single X read, LDS-staged transpose (verified R3) ------
__global__ __launch_bounds__(256, 4)
void prep_kernel(const float* __restrict__ X, unsigned short* __restrict__ Img) {
  __shared__ __align__(16) unsigned short rowbf[8 * 256];  // 4 KB bf16 stage
  const int b    = blockIdx.x & 3;
  const int sub  = blockIdx.x >> 2;   // 0..511
  const int t    = sub >> 3;
  const int part = sub & 7;
  const int tid  = threadIdx.x;
  const float* src = X + ((size_t)b * NTOK + t * 64 + part * 8) * DIM;
  unsigned short* dst = Img + ((size_t)(b * 64 + t)) * TILE_ELEMS;
  {
    const int r = tid >> 5;   // row within the 8-row slab
    const int c = tid & 31;   // 16B chunk within the row
    const float* s = src + r * DIM + c * 8;
    f32x4 f0 = *(const f32x4*)s;
    f32x4 f1 = *(const f32x4*)(s + 4);
    union { unsigned u[4]; u32x4 v; } p;
    p.u[0] = pack2bf(f0[0], f0[1]);
    p.u[1] = pack2bf(f0[2], f0[3]);
    p.u[2] = pack2bf(f1[0], f1[1]);
    p.u[3] = pack2bf(f1[2], f1[3]);
    const int gr = part * 8 + r;
    *(u32x4*)(dst + gr * 256 + ((c ^ (gr & 7)) << 3)) = p.v;
    *(u32x4*)(&rowbf[r * 256 + c * 8]) = p.v;
  }
  __syncthreads();
  {
    const int d = tid;        // one column per thread
    union { unsigned short s[8]; u32x4 v; } p;
    #pragma unroll
    for (int i = 0; i < 8; ++i) p.s[i] = rowbf[i * 256 + d];
    *(u32x4*)(dst + 16384 + part * 2048 + d * 8) = p.v;
  }
}

// ---- flash-attention v10 (session champion, verified 75.9us) -------------
// Specialized waves (4 QK + 4 PV) + 2-deep deferred softmax (T15):
// QK wave: keys role*16..+15 x all 64 q rows; K frags straight from the
//   L2/L3-hot Ks image; softmax of tile t-1 deferred to iter t, placed
//   between K-load issue and the MFMA cluster (VALU hides under K latency
//   and co-issues against PV's MFMA burst).
// PV wave: d-quarter role*64..+63; V register double-buffered from the Kt
//   image (consumed at t+2 -> 2 iters to land); P consumed via LDS.
// Register budget is exactly saturated at 2 waves/SIMD (u[32]=128 VGPRs
// overlaid: QK's Q frags <-> PV's acc+V sets). R11/R13 proved any persistent
// addition spills; R12 proved K latency is already hidden; R5/R8/R9 proved
// traffic relocation is wall-neutral. This is the structural floor of the
// design family.
#define PV_TAIL(PRD, SB)                                                       \
  {                                                                            \
    const unsigned short* prd = (PRD);                                         \
    _Pragma("unroll")                                                          \
    for (int ks = 0; ks < 2; ++ks) {                                           \
      const int pos = (ks * 4 + quad) ^ ((ln >> 3) << 1);                      \
      _Pragma("unroll")                                                        \
      for (int s = 0; s < 4; ++s) {                                            \
        short8 ap = *(const short8*)(&prd[(s * 16 + ln) * P_STRIDE +           \
                                          (pos << 3)]);                        \
        _Pragma("unroll")                                                      \
        for (int dt = 0; dt < 4; ++dt)                                         \
          u[s * 4 + dt] = __builtin_amdgcn_mfma_f32_16x16x32_bf16(             \
              ap, __builtin_bit_cast(short8, u[(SB) + ks * 4 + dt]),           \
              u[s * 4 + dt], 0, 0, 0);                                         \
      }                                                                        \
    }                                                                          \
  }

#define FA_STEP(T, SETB)                                                       \
  {                                                                            \
    const int t_ = (T);                                                        \
    __syncthreads();  /* publishes P(t-2) in pb[t&1]; orders pb reuse */       \
    if (!isQK) {                                                               \
      if (t_ > 1) {                                                            \
        __builtin_amdgcn_s_setprio(1);                                         \
        PV_TAIL(pb[t_ & 1], SETB);   /* P(t-2) x V(t-2) */                     \
        __builtin_amdgcn_s_setprio(0);                                         \
      }                                                                        \
      { /* reload set with V(t); consumed at t+2 -> 2 iters to land */         \
        const unsigned short* vt = vtg + (size_t)t_ * TILE_ELEMS;              \
        _Pragma("unroll")                                                      \
        for (int ks = 0; ks < 2; ++ks)                                         \
          _Pragma("unroll")                                                    \
          for (int dt = 0; dt < 4; ++dt)                                       \
            u[(SETB) + ks * 4 + dt] = __builtin_bit_cast(f32x4,                \
                *(const short8*)(vt + (ks * 4 + quad) * 2048 + dt * 128));     \
      }                                                                        \
    } else {                                                                   \
      /* 1) issue K(t) loads (L2/L3-hot) */                                    \
      const unsigned short* kR =                                               \
          imgb + (size_t)t_ * TILE_ELEMS + (role * 16 + ln) * 256;             \
      short8 bk[8];                                                            \
      _Pragma("unroll")                                                        \
      for (int ds = 0; ds < 8; ++ds)                                           \
        bk[ds] = *(const short8*)(kR + (((ds * 4 + quad) ^ swz) << 3));        \
      /* 2) deferred softmax of tile t-1 (VALU; overlaps K latency+MFMA) */    \
      if (t_ > 0) expstore((t_ & 1) ^ 1);                                      \
      /* 3) QK MFMA into sfo (first ds starts from zero) */                    \
      __builtin_amdgcn_s_setprio(1);                                           \
      _Pragma("unroll")                                                        \
      for (int s = 0; s < 4; ++s)                                              \
        sfo[s] = __builtin_amdgcn_mfma_f32_16x16x32_bf16(                      \
            __builtin_bit_cast(short8, u[s * 8]), bk[0], (f32x4)(0.0f),        \
            0, 0, 0);                                                          \
      _Pragma("unroll")                                                        \
      for (int ds = 1; ds < 8; ++ds)                                           \
        _Pragma("unroll")                                                      \
        for (int s = 0; s < 4; ++s)                                            \
          sfo[s] = __builtin_amdgcn_mfma_f32_16x16x32_bf16(                    \
              __builtin_bit_cast(short8, u[s * 8 + ds]), bk[ds], sfo[s],       \
              0, 0, 0);                                                        \
      __builtin_amdgcn_s_setprio(0);                                           \
    }                                                                          \
  }

__global__ __launch_bounds__(512, 1)
void fa_kernel(const unsigned short* __restrict__ Img, float* __restrict__ Out) {
  __shared__ __align__(16) unsigned short pb[2][64 * P_STRIDE]; // 18 KB P dbuf
  __shared__ float lbuf[64][4];                                 // 1 KB

  const int tid  = threadIdx.x;
  const int b    = blockIdx.x & 3;
  const int qblk = blockIdx.x >> 2;
  const int wave = tid >> 6;
  const int lane = tid & 63;
  const int ln   = lane & 15;
  const int quad = lane >> 4;
  const int swz  = ln & 7;
  const bool isQK = wave < 4;
  const int  role = wave & 3;  // QK: key-16 group; PV: d-quarter

  const unsigned short* imgb = Img + (size_t)b * 64 * TILE_ELEMS;

  const float c2 = 0.0901684400f;  // log2(e)/sqrt(256)

  // P write constants (QK waves): kc = role*2 + (ln>>3); pos = kc ^ (2*(quad>>1))
  const int pwPos = ((role * 2 + (ln >> 3)) ^ ((quad >> 1) << 1)) << 3;
  const int pwCol = ln & 7;

  // PV: V-frag base in Kt image
  const unsigned short* vtg = imgb + 16384 + (size_t)(role * 64 + ln) * 8;

  float lrow[4][4] = {{0,0,0,0},{0,0,0,0},{0,0,0,0},{0,0,0,0}};
  f32x4 sfo[4];  // QK: scores of the PREVIOUS tile (deferred softmax)

  // Register overlay: QK waves -> aQ[s][ds] = u[s*8+ds];
  //                   PV waves -> o[s][dt] = u[s*4+dt], V sets at u[16+set*8+..]
  f32x4 u[32];
  if (isQK) {
    #pragma unroll
    for (int s = 0; s < 4; ++s) {
      const unsigned short* qrow =
          imgb + (size_t)qblk * TILE_ELEMS + (s * 16 + ln) * 256;
      #pragma unroll
      for (int ds = 0; ds < 8; ++ds)
        u[s * 8 + ds] = __builtin_bit_cast(f32x4,
            *(const short8*)(qrow + (((ds * 4 + quad) ^ swz) << 3)));
    }
  } else {
    #pragma unroll
    for (int i = 0; i < 16; ++i) u[i] = (f32x4)(0.0f);
  }

  // deferred-softmax of sfo -> pb[pwbuf] (QK waves only)
  auto expstore = [&](int pwbuf) __attribute__((always_inline)) {
    unsigned short* pw = pb[pwbuf];
    #pragma unroll
    for (int s = 0; s < 4; ++s) {
      unsigned pd[4];
      #pragma unroll
      for (int j = 0; j < 4; ++j) {
        float p0 = __builtin_amdgcn_exp2f(sfo[s][j] * c2);
        lrow[s][j] += p0;
        unsigned q0 = __builtin_bit_cast(unsigned, p0);
        unsigned n0 = (unsigned)__builtin_amdgcn_mov_dpp((int)q0, 0xB1,
                                                         0xF, 0xF, true);
        pd[j] = pack2bf(p0, __builtin_bit_cast(float, n0));
      }
      if ((ln & 1) == 0) {
        #pragma unroll
        for (int j = 0; j < 4; ++j)
          *(unsigned*)(&pw[(s * 16 + quad * 4 + j) * P_STRIDE +
                           pwPos + pwCol]) = pd[j];
      }
    }
  };

  #pragma unroll 1
  for (int tt = 0; tt < 64; tt += 2) {
    FA_STEP(tt, 16);       // even t: V set base 16
    FA_STEP(tt + 1, 24);   // odd  t: V set base 24
  }
  // state: P(62) in pb[0] (stored at t=63); sfo = sf(63);
  //        V(62) in set 16, V(63) in set 24.

  __syncthreads();  // publishes P(62)
  if (isQK) {
    expstore(1);    // P(63) -> pb[1]
  } else {
    PV_TAIL(pb[0], 16);  // P(62) x V(62)
  }
  __syncthreads();  // publishes P(63)

  if (isQK) {
    // merge l over the 16 key-lanes of this role
    #pragma unroll
    for (int off = 1; off < 16; off <<= 1)
      #pragma unroll
      for (int s = 0; s < 4; ++s)
        #pragma unroll
        for (int j = 0; j < 4; ++j)
          lrow[s][j] += __shfl_xor(lrow[s][j], off, 64);
    if (ln == 0) {
      #pragma unroll
      for (int s = 0; s < 4; ++s)
        #pragma unroll
        for (int j = 0; j < 4; ++j)
          lbuf[s * 16 + quad * 4 + j][role] = lrow[s][j];
    }
  } else {
    PV_TAIL(pb[1], 24);  // P(63) x V(63)
  }
  __syncthreads();  // lbuf ready

  if (!isQK) {
    float* outB = Out + (size_t)(b * NTOK + qblk * 64) * DIM + role * 64;
    #pragma unroll
    for (int s = 0; s < 4; ++s) {
      #pragma unroll
      for (int j = 0; j < 4; ++j) {
        const int row = s * 16 + quad * 4 + j;
        f32x4 lv = *(const f32x4*)lbuf[row];
        const float rl = 1.0f / (lv[0] + lv[1] + lv[2] + lv[3]);
        #pragma unroll
        for (int dt = 0; dt < 4; ++dt)
          outB[(size_t)row * DIM + dt * 16 + ln] = u[s * 4 + dt][j] * rl;
      }
    }
  }
}

extern "C" void kernel_launch(void* const* d_in, const int* in_sizes, int n_in,
                              void* d_out, int out_size, void* d_ws, size_t ws_size,
                              hipStream_t stream) {
  const float* X = (const float*)d_in[0];       // x: fp32 [4,4096,256]
  float* Out = (float*)d_out;                   // fp32 [4,4096,256]
  unsigned short* Img = (unsigned short*)d_ws;  // 16 MB bf16 tile images
  (void)in_sizes; (void)n_in; (void)out_size; (void)ws_size;
  hipLaunchKernelGGL(prep_kernel, dim3(2048), dim3(256), 0, stream, X, Img);
  hipLaunchKernelGGL(fa_kernel, dim3(256), dim3(512), 0, stream, Img, Out);
}